// Round 1
// baseline (79.874 us; speedup 1.0000x reference)
//
#include <hip/hip_runtime.h>

// Problem constants (from reference)
constexpr int S = 256;          // N_SINES
constexpr int N = 512;          // control points
constexpr int R = 32;           // RESAMPLING_FACTOR
constexpr int OUT_N = N * R;    // 16384 output samples per batch

// ---------------------------------------------------------------------------
// Kernel 1: per-(b,s) row prep. One 64-lane wave per row, no barriers.
//   G[n] = 16*f0 + sum_{m<n} 16*(f_m + f_{m+1})   (Hz-sample units)
// computed exactly in fp64 via register shuffle scan, then reduced mod 44100
// and packed with the interpolation coefficients into a 32B struct:
//   W[b][s][n] = { g_mod, f_n, df_n, a_n, da_n, pad, pad, pad }
// so the synth kernel is pure fp32 with 2 loads/sine from one cache line.
// ---------------------------------------------------------------------------
__global__ __launch_bounds__(64) void prep_pack_kernel(
    const float* __restrict__ freq, const float* __restrict__ amp,
    float* __restrict__ W) {
  const int row = blockIdx.x;          // b*S + s
  const int l = threadIdx.x;           // lane 0..63, handles n = 8l..8l+7
  const float* f = freq + (size_t)row * N + l * 8;
  const float* a = amp  + (size_t)row * N + l * 8;

  const float4 fa = *reinterpret_cast<const float4*>(f);
  const float4 fb = *reinterpret_cast<const float4*>(f + 4);
  const float4 aa = *reinterpret_cast<const float4*>(a);
  const float4 ab = *reinterpret_cast<const float4*>(a + 4);

  float fv[9] = {fa.x, fa.y, fa.z, fa.w, fb.x, fb.y, fb.z, fb.w, 0.0f};
  float av[9] = {aa.x, aa.y, aa.z, aa.w, ab.x, ab.y, ab.z, ab.w, 0.0f};
  fv[8] = __shfl_down(fa.x, 1);        // f[8l+8] (garbage on lane 63, unused)
  av[8] = __shfl_down(aa.x, 1);

  // local inclusive prefix of increments inc[m] = 16*(f_m + f_{m+1}), m<511
  double p[8];
  double run = 0.0;
  #pragma unroll
  for (int i = 0; i < 8; ++i) {
    const int n = l * 8 + i;
    const double inc =
        (n < N - 1) ? 16.0 * ((double)fv[i] + (double)fv[i + 1]) : 0.0;
    run += inc;
    p[i] = run;
  }

  // wave-wide inclusive scan of per-lane sums (fp64 shuffles), no LDS
  double x = run;
  #pragma unroll
  for (int off = 1; off < 64; off <<= 1) {
    const double y = __shfl_up(x, off);
    if (l >= off) x += y;
  }
  const double excl = x - run;                 // sum of lanes < l
  const float f0 = __shfl(fa.x, 0);
  const double base = 16.0 * (double)f0;

  float* wrow = W + ((size_t)row * N + l * 8) * 8;
  #pragma unroll
  for (int i = 0; i < 8; ++i) {
    const int n = l * 8 + i;
    const double g = base + excl + (i ? p[i - 1] : 0.0);
    const double gm = g - floor(g / 44100.0) * 44100.0;   // exact-ish mod
    const float fn = fv[i];
    const float df = (n < N - 1) ? fv[i + 1] - fn : 0.0f;
    const float an = av[i];
    const float da = (n < N - 1) ? av[i + 1] - an : 0.0f;
    const float4 o{(float)gm, fn, df, an};
    *reinterpret_cast<float4*>(wrow + i * 8) = o;
    wrow[i * 8 + 4] = da;
  }
}

// ---------------------------------------------------------------------------
// Kernel 2: synthesize. Block = 64 samples x 8 sine-chunks (512 threads,
// 8 waves -> 32 waves/CU at 1024 blocks). Pure fp32 inner loop:
//   P = g_mod + c1*f_n + c2*df_n      (Hz-samples, mod 44100 ambiguity OK)
//   r = frac(P/44100)                  -> v_sin_f32 takes revolutions
// Region coefficients (per output sample j):
//   j <  16         : n=0,   c1=j-15 (uses g_mod[0]=16*f0 mod 44100), c2=wa=0
//   16<=j<16368     : n=(j-16)>>5, k=(j-16)&31, c1=k+1, c2=(k+1)^2/64,
//                     wa=(k+0.5)/32
//   j >= 16368      : n=511, c1=j-16367, c2=wa=0 (df=da=0 packed at n=511)
// ---------------------------------------------------------------------------
__global__ __launch_bounds__(512) void synth_sin_kernel(
    const float* __restrict__ W, float* __restrict__ out) {
  const int tid = threadIdx.x;
  const int split = tid >> 6;                 // sine chunk 0..7 (32 sines)
  const int samp = tid & 63;
  const int gid = blockIdx.x * 64 + samp;     // global output sample id
  const int b = gid >> 14;                    // / OUT_N
  const int j = gid & (OUT_N - 1);

  int n;
  float c1, c2, wa;
  if (j < 16) {
    n = 0; c1 = (float)(j - 15); c2 = 0.0f; wa = 0.0f;
  } else if (j >= OUT_N - 16) {
    n = N - 1; c1 = (float)(j - (OUT_N - 16) + 1); c2 = 0.0f; wa = 0.0f;
  } else {
    const int jj = j - 16;
    n = jj >> 5;
    const int k = jj & 31;
    c1 = (float)(k + 1);
    c2 = (float)((k + 1) * (k + 1)) * (1.0f / 64.0f);
    wa = ((float)k + 0.5f) * (1.0f / 32.0f);
  }

  const float* wp = W + (((size_t)b * S + split * (S / 8)) * N + n) * 8;
  constexpr float inv_fs = 1.0f / 44100.0f;
  float acc = 0.0f;
  #pragma unroll 8
  for (int s = 0; s < S / 8; ++s) {
    const float4 v = *reinterpret_cast<const float4*>(wp);  // g, fn, df, an
    const float da = wp[4];
    float P = fmaf(c2, v.z, fmaf(c1, v.y, v.x));
    float r = P * inv_fs;
    r = r - floorf(r);                        // frac -> [0,1) revolutions
    const float sv = __builtin_amdgcn_sinf(r);
    const float av = fmaf(da, wa, v.w);
    acc = fmaf(av, sv, acc);
    wp += (size_t)N * 8;
  }

  __shared__ float red[512];
  red[tid] = acc;
  __syncthreads();
  if (tid < 64) {
    float v = 0.0f;
    #pragma unroll
    for (int c = 0; c < 8; ++c) v += red[tid + 64 * c];
    out[gid] = v;
  }
}

// ---------------------------------------------------------------------------
extern "C" void kernel_launch(void* const* d_in, const int* in_sizes, int n_in,
                              void* d_out, int out_size, void* d_ws, size_t ws_size,
                              hipStream_t stream) {
  const float* freq = (const float*)d_in[0];
  const float* amp  = (const float*)d_in[1];
  float* out = (float*)d_out;
  float* W = (float*)d_ws;                    // [B][S][N] x 8 floats = 16 MiB

  const int B = in_sizes[0] / (S * N);        // 4

  prep_pack_kernel<<<dim3(B * S), dim3(64), 0, stream>>>(freq, amp, W);
  synth_sin_kernel<<<dim3(B * OUT_N / 64), dim3(512), 0, stream>>>(W, out);
}